// Round 2
// baseline (1546.308 us; speedup 1.0000x reference)
//
#include <hip/hip_runtime.h>
#include <math.h>

// LinearBlock: x -> LN1 -> QKV -> linear attention -> Wo+bias+res -> LN2 -> FFN(gelu) -> +res
// B=4, T=8192, D=768, H=12, HD=64, DFF=3072.
// Device buffers: fp32 in / fp32 out (per reference dtypes). Internal: bf16 MFMA, fp32 acc.

#define DEV __device__ __forceinline__

typedef __attribute__((ext_vector_type(8))) short s16x8;   // 8 x bf16 fragment (4 VGPRs)
typedef __attribute__((ext_vector_type(4))) float f32x4;   // MFMA accumulator

static constexpr int    Bb   = 4;
static constexpr int    Tt   = 8192;
static constexpr int    Dd   = 768;
static constexpr int    Hh   = 12;
static constexpr int    HD   = 64;
static constexpr size_t Mrows = (size_t)Bb * Tt;           // 32768

DEV float bf2f(unsigned short u) {
    union { unsigned int i; float f; } c; c.i = ((unsigned int)u) << 16; return c.f;
}
DEV unsigned short f2bf(float f) {
    union { float f; unsigned int i; } c; c.f = f;
    unsigned int r = c.i + 0x7fffu + ((c.i >> 16) & 1u);   // RNE
    return (unsigned short)(r >> 16);
}

// ---------------------------------------------------------------------------
// Transpose + convert: fp32 in[R][C] -> bf16 out[C][R]
// ---------------------------------------------------------------------------
__global__ __launch_bounds__(256)
void transpose_f2b(const float* __restrict__ in, unsigned short* __restrict__ out,
                   int R, int C) {
    __shared__ float tile[32][33];
    const int c0 = blockIdx.x * 32, r0 = blockIdx.y * 32;
    const int tx = threadIdx.x, ty = threadIdx.y;          // (32, 8)
    #pragma unroll
    for (int i = 0; i < 32; i += 8)
        tile[ty + i][tx] = in[(size_t)(r0 + ty + i) * C + c0 + tx];
    __syncthreads();
    #pragma unroll
    for (int i = 0; i < 32; i += 8)
        out[(size_t)(c0 + ty + i) * R + r0 + tx] = f2bf(tile[tx][ty + i]);
}

// ---------------------------------------------------------------------------
// LayerNorm over D=768. BF16IN: 0 = fp32 input, 1 = bf16 input. Output bf16.
// ---------------------------------------------------------------------------
template <int BF16IN>
__global__ __launch_bounds__(256)
void ln_kernel(const void* __restrict__ xin, const float* __restrict__ g,
               const float* __restrict__ bvec, unsigned short* __restrict__ out) {
    __shared__ float red[4];
    const int tid = threadIdx.x;
    const size_t base = (size_t)blockIdx.x * Dd;
    float v[3];
    #pragma unroll
    for (int i = 0; i < 3; ++i) {
        const size_t idx = base + tid + i * 256;
        if (BF16IN) v[i] = bf2f(((const unsigned short*)xin)[idx]);
        else        v[i] = ((const float*)xin)[idx];
    }
    float s = v[0] + v[1] + v[2];
    #pragma unroll
    for (int o = 32; o >= 1; o >>= 1) s += __shfl_xor(s, o);
    if ((tid & 63) == 0) red[tid >> 6] = s;
    __syncthreads();
    s = red[0] + red[1] + red[2] + red[3];
    const float mu = s * (1.0f / Dd);
    __syncthreads();
    float q = 0.f;
    #pragma unroll
    for (int i = 0; i < 3; ++i) { const float d = v[i] - mu; q += d * d; }
    #pragma unroll
    for (int o = 32; o >= 1; o >>= 1) q += __shfl_xor(q, o);
    if ((tid & 63) == 0) red[tid >> 6] = q;
    __syncthreads();
    q = red[0] + red[1] + red[2] + red[3];
    const float rstd = rsqrtf(q * (1.0f / Dd) + 1e-5f);
    #pragma unroll
    for (int i = 0; i < 3; ++i) {
        const int c = tid + i * 256;
        out[base + c] = f2bf((v[i] - mu) * rstd * g[c] + bvec[c]);
    }
}

// ---------------------------------------------------------------------------
// GEMM: C[M,N] = A[M,K] @ BT[N,K]^T, bf16 in, fp32 acc, fused epilogue.
// 128x128 tile, 4 waves (2x2), each wave 64x64 = 4x4 frags of 16x16x32 MFMA.
// ---------------------------------------------------------------------------
#define EPI_QKV  0   // out bf16 Q/K/V triple (each M*768), elu+1 on Q,K
#define EPI_X2   1   // out bf16 = acc + bias[col] + f32res[row,col]      (x2 = att + x)
#define EPI_GELU 2   // out bf16 = gelu(acc + bias[col])
#define EPI_OUT1 3   // out f32  = acc + bias[col] + bf16res[row,col]     (first FFN2 half)
#define EPI_OUT2 4   // out f32 += acc                                    (second FFN2 half)

template <int EPI, int K>
__global__ __launch_bounds__(256)
void gemm_bt(const unsigned short* __restrict__ A,
             const unsigned short* __restrict__ BT,
             const float* __restrict__ bias,
             const void* __restrict__ res,
             void* __restrict__ out, int N) {
    const int nt = blockIdx.x, mt = blockIdx.y;
    const int m0 = mt * 128, n0 = nt * 128;
    const int tid = threadIdx.x;
    const int lane = tid & 63, w = tid >> 6;
    const int wm = w >> 1, wn = w & 1;
    const int l15 = lane & 15, lk = lane >> 4;

    __shared__ __align__(16) unsigned short sA[128][40];   // pad 32->40 for bank spread
    __shared__ __align__(16) unsigned short sB[128][40];

    f32x4 acc[4][4] = {};

    for (int kt = 0; kt < K; kt += 32) {
        #pragma unroll
        for (int rr = 0; rr < 2; ++rr) {
            const int f = rr * 256 + tid;
            const int row = f >> 2, ch = (f & 3) * 8;
            const s16x8 av = *(const s16x8*)(A + (size_t)(m0 + row) * K + kt + ch);
            const s16x8 bv = *(const s16x8*)(BT + (size_t)(n0 + row) * K + kt + ch);
            *(s16x8*)(&sA[row][ch]) = av;
            *(s16x8*)(&sB[row][ch]) = bv;
        }
        __syncthreads();
        s16x8 af[4], bf[4];
        #pragma unroll
        for (int i = 0; i < 4; ++i) {
            af[i] = *(const s16x8*)(&sA[wm * 64 + i * 16 + l15][lk * 8]);
            bf[i] = *(const s16x8*)(&sB[wn * 64 + i * 16 + l15][lk * 8]);
        }
        #pragma unroll
        for (int i = 0; i < 4; ++i)
            #pragma unroll
            for (int j = 0; j < 4; ++j)
                acc[i][j] = __builtin_amdgcn_mfma_f32_16x16x32_bf16(af[i], bf[j], acc[i][j], 0, 0, 0);
        __syncthreads();
    }

    // D frag mapping: col = lane&15, row = (lane>>4)*4 + r   [guide m89]
    #pragma unroll
    for (int i = 0; i < 4; ++i) {
        #pragma unroll
        for (int j = 0; j < 4; ++j) {
            const int col = n0 + wn * 64 + j * 16 + l15;
            #pragma unroll
            for (int r = 0; r < 4; ++r) {
                const int row = m0 + wm * 64 + i * 16 + lk * 4 + r;
                float v = acc[i][j][r];
                if (EPI == EPI_QKV) {
                    const int which = col / 768;
                    const int cc = col - which * 768;
                    if (which < 2) v = (v > 0.f) ? (v + 1.f) : __expf(v);   // elu(v)+1
                    ((unsigned short*)out)[(size_t)which * (Mrows * Dd) + (size_t)row * Dd + cc] = f2bf(v);
                } else if (EPI == EPI_X2) {
                    v += bias[col] + ((const float*)res)[(size_t)row * N + col];
                    ((unsigned short*)out)[(size_t)row * N + col] = f2bf(v);
                } else if (EPI == EPI_GELU) {
                    v += bias[col];
                    v = 0.5f * v * (1.0f + erff(v * 0.70710678118654752f));
                    ((unsigned short*)out)[(size_t)row * N + col] = f2bf(v);
                } else if (EPI == EPI_OUT1) {
                    v += bias[col] + bf2f(((const unsigned short*)res)[(size_t)row * N + col]);
                    ((float*)out)[(size_t)row * N + col] = v;
                } else {  // EPI_OUT2
                    ((float*)out)[(size_t)row * N + col] += v;
                }
            }
        }
    }
}

// ---------------------------------------------------------------------------
// K_sum[bh][d] = sum_t K[b,t,h,d]
// ---------------------------------------------------------------------------
__global__ __launch_bounds__(256)
void ksum_kernel(const unsigned short* __restrict__ Km, float* __restrict__ ksum) {
    const int bh = blockIdx.x;
    const int b = bh / Hh, h = bh - b * Hh;
    const int tid = threadIdx.x;
    const int d = tid & 63, sl = tid >> 6;
    const size_t colbase = ((size_t)b * Tt) * Dd + h * HD + d;
    float s = 0.f;
    #pragma unroll 8
    for (int t = sl * 2048; t < (sl + 1) * 2048; ++t)
        s += bf2f(Km[colbase + (size_t)t * Dd]);
    __shared__ float red[4][64];
    red[sl][d] = s;
    __syncthreads();
    if (sl == 0) ksum[bh * 64 + d] = red[0][d] + red[1][d] + red[2][d] + red[3][d];
}

// ---------------------------------------------------------------------------
// Partial KV: part[bh][chunk][d][e] = sum_{t in chunk} K[t,d] * V[t,e]  (chunk = 1024 t)
// ---------------------------------------------------------------------------
__global__ __launch_bounds__(256)
void kv_partial(const unsigned short* __restrict__ Km, const unsigned short* __restrict__ Vm,
                float* __restrict__ part) {
    const int ck = blockIdx.x, bh = blockIdx.y;
    const int b = bh / Hh, h = bh - b * Hh;
    const int tid = threadIdx.x;
    const int e = tid & 63, dg = tid >> 6;               // wave-uniform dg
    __shared__ float sK[32][64], sV[32][64];
    float acc[16] = {};
    const size_t rowbase = ((size_t)b * Tt + (size_t)ck * 1024) * Dd + h * HD;
    const int rw = tid >> 3, cv = (tid & 7) * 8;
    for (int ts = 0; ts < 1024; ts += 32) {
        const s16x8 k8 = *(const s16x8*)(Km + rowbase + (size_t)(ts + rw) * Dd + cv);
        const s16x8 v8 = *(const s16x8*)(Vm + rowbase + (size_t)(ts + rw) * Dd + cv);
        float kf[8], vf[8];
        #pragma unroll
        for (int j = 0; j < 8; ++j) {
            kf[j] = bf2f((unsigned short)k8[j]);
            vf[j] = bf2f((unsigned short)v8[j]);
        }
        __syncthreads();   // protect previous iteration's readers
        *(float4*)(&sK[rw][cv]) = *(const float4*)&kf[0];
        *(float4*)(&sK[rw][cv + 4]) = *(const float4*)&kf[4];
        *(float4*)(&sV[rw][cv]) = *(const float4*)&vf[0];
        *(float4*)(&sV[rw][cv + 4]) = *(const float4*)&vf[4];
        __syncthreads();
        #pragma unroll 4
        for (int tt = 0; tt < 32; ++tt) {
            const float vv = sV[tt][e];
            const float4* kp = (const float4*)(&sK[tt][dg * 16]);  // wave-broadcast
            const float4 k0 = kp[0], k1 = kp[1], k2 = kp[2], k3 = kp[3];
            acc[0]  += k0.x * vv; acc[1]  += k0.y * vv; acc[2]  += k0.z * vv; acc[3]  += k0.w * vv;
            acc[4]  += k1.x * vv; acc[5]  += k1.y * vv; acc[6]  += k1.z * vv; acc[7]  += k1.w * vv;
            acc[8]  += k2.x * vv; acc[9]  += k2.y * vv; acc[10] += k2.z * vv; acc[11] += k2.w * vv;
            acc[12] += k3.x * vv; acc[13] += k3.y * vv; acc[14] += k3.z * vv; acc[15] += k3.w * vv;
        }
    }
    float* op = part + ((size_t)bh * 8 + ck) * 4096 + (size_t)dg * 16 * 64 + e;
    #pragma unroll
    for (int i = 0; i < 16; ++i) op[(size_t)i * 64] = acc[i];
}

__global__ __launch_bounds__(256)
void kv_reduce(const float* __restrict__ part, float* __restrict__ kv) {
    const int bh = blockIdx.x;
    const int tid = threadIdx.x;
    #pragma unroll
    for (int j = 0; j < 16; ++j) {
        const int i = j * 256 + tid;
        float s = 0.f;
        #pragma unroll
        for (int c = 0; c < 8; ++c) s += part[((size_t)bh * 8 + c) * 4096 + i];
        kv[(size_t)bh * 4096 + i] = s;
    }
}

// ---------------------------------------------------------------------------
// ctx[b,t,h,e] = (sum_d Q[t,d] * KV[d,e]) / (sum_d Q[t,d]*Ksum[d] + eps)
// ---------------------------------------------------------------------------
__global__ __launch_bounds__(256)
void ctx_kernel(const unsigned short* __restrict__ Q, const float* __restrict__ kv,
                const float* __restrict__ ksum, unsigned short* __restrict__ ctx) {
    const int bh = blockIdx.y;
    const int b = bh / Hh, h = bh - b * Hh;
    const int tid = threadIdx.x;
    const int e = tid & 63, w = tid >> 6;
    float kcol[64];
    #pragma unroll
    for (int d = 0; d < 64; ++d) kcol[d] = kv[(size_t)bh * 4096 + d * 64 + e];
    const float ks = ksum[bh * 64 + e];
    for (int j = 0; j < 16; ++j) {
        const int t = blockIdx.x * 64 + j * 4 + w;
        const size_t off = ((size_t)b * Tt + t) * Dd + h * HD;
        const float q = bf2f(Q[off + e]);
        float zp = q * ks;
        #pragma unroll
        for (int o = 32; o >= 1; o >>= 1) zp += __shfl_xor(zp, o);
        const float zi = 1.0f / (zp + 1e-6f);
        float a = 0.f;
        #pragma unroll
        for (int d = 0; d < 64; ++d) a += __shfl(q, d) * kcol[d];
        ctx[off + e] = f2bf(a * zi);
    }
}

// ---------------------------------------------------------------------------
extern "C" void kernel_launch(void* const* d_in, const int* in_sizes, int n_in,
                              void* d_out, int out_size, void* d_ws, size_t ws_size,
                              hipStream_t stream) {
    (void)in_sizes; (void)n_in; (void)out_size; (void)ws_size;
    const float* x    = (const float*)d_in[0];
    const float* Wq   = (const float*)d_in[1];
    const float* Wk   = (const float*)d_in[2];
    const float* Wv   = (const float*)d_in[3];
    const float* Wo   = (const float*)d_in[4];
    const float* bo   = (const float*)d_in[5];
    const float* ln1g = (const float*)d_in[6];
    const float* ln1b = (const float*)d_in[7];
    const float* ln2g = (const float*)d_in[8];
    const float* ln2b = (const float*)d_in[9];
    const float* W1   = (const float*)d_in[10];
    const float* b1   = (const float*)d_in[11];
    const float* W2   = (const float*)d_in[12];
    const float* b2   = (const float*)d_in[13];
    float* outp = (float*)d_out;

    // workspace layout (total ~212.3 MiB)
    char* ws = (char*)d_ws;
    const size_t SZ = Mrows * Dd * 2;                           // 50,331,648 B (bf16 [M][768])
    unsigned short* xn   = (unsigned short*)(ws + 0);           // s0
    unsigned short* Qb   = (unsigned short*)(ws + SZ);          // s1
    unsigned short* Kb   = (unsigned short*)(ws + 2 * SZ);      // s2 (later: ctx)
    unsigned short* Vb   = (unsigned short*)(ws + 3 * SZ);      // s3 (later: x2 bf16)
    char* p = ws + 4 * SZ;
    float* part  = (float*)p;  p += (size_t)48 * 8 * 4096 * 4;  // 6,291,456
    float* kvf   = (float*)p;  p += (size_t)48 * 4096 * 4;      // 786,432
    float* ksumf = (float*)p;  p += (size_t)48 * 64 * 4;        // 12,288
    unsigned short* wqkvT = (unsigned short*)p; p += (size_t)2304 * 768 * 2;
    unsigned short* woT   = (unsigned short*)p; p += (size_t)768 * 768 * 2;
    unsigned short* w1T   = (unsigned short*)p; p += (size_t)3072 * 768 * 2;
    unsigned short* w2aT  = (unsigned short*)p; p += (size_t)768 * 1536 * 2;
    unsigned short* w2bT  = (unsigned short*)p; p += (size_t)768 * 1536 * 2;
    unsigned short* ctxb = Kb;          // K dead after kv stats
    unsigned short* x2b  = Vb;          // V dead after kv stats; x2 = att + x (bf16)
    unsigned short* ff1  = Qb;          // halves of ff1: M*1536 bf16 = slots s1+s2

    const dim3 blk(256);
    const dim3 tb(32, 8);

    // 1) weight transposes + bf16 convert
    transpose_f2b<<<dim3(24, 24), tb, 0, stream>>>(Wq, wqkvT, 768, 768);
    transpose_f2b<<<dim3(24, 24), tb, 0, stream>>>(Wk, wqkvT + 589824, 768, 768);
    transpose_f2b<<<dim3(24, 24), tb, 0, stream>>>(Wv, wqkvT + 2 * 589824, 768, 768);
    transpose_f2b<<<dim3(24, 24), tb, 0, stream>>>(Wo, woT, 768, 768);
    transpose_f2b<<<dim3(96, 24), tb, 0, stream>>>(W1, w1T, 768, 3072);      // -> [3072][768]
    transpose_f2b<<<dim3(24, 48), tb, 0, stream>>>(W2, w2aT, 1536, 768);     // rows 0..1535
    transpose_f2b<<<dim3(24, 48), tb, 0, stream>>>(W2 + (size_t)1536 * 768, w2bT, 1536, 768);

    // 2) LN1 (fp32 x -> bf16 xn)
    ln_kernel<0><<<32768, blk, 0, stream>>>(x, ln1g, ln1b, xn);

    // 3) fused QKV projection (N = 2304), elu+1 on Q,K
    gemm_bt<EPI_QKV, 768><<<dim3(18, 256), blk, 0, stream>>>(xn, wqkvT, nullptr, nullptr, Qb, 2304);

    // 4) linear attention statistics
    ksum_kernel<<<48, blk, 0, stream>>>(Kb, ksumf);
    kv_partial<<<dim3(8, 48), blk, 0, stream>>>(Kb, Vb, part);
    kv_reduce<<<48, blk, 0, stream>>>(part, kvf);

    // 5) ctx = (Q @ KV) / (Q . Ksum + eps)  -> ctxb (= Kb)
    ctx_kernel<<<dim3(128, 48), blk, 0, stream>>>(Qb, kvf, ksumf, ctxb);

    // 6) Wo projection + bias + residual(x fp32) -> x2 bf16 (= Vb)
    gemm_bt<EPI_X2, 768><<<dim3(6, 256), blk, 0, stream>>>(ctxb, woT, bo, x, x2b, 768);

    // 7) LN2 (bf16 x2 -> bf16 xn)
    ln_kernel<1><<<32768, blk, 0, stream>>>(x2b, ln2g, ln2b, xn);

    // 8) FFN in two halves (ff1-half = M x 1536 bf16 in s1+s2)
    //    half 0: out  = gelu(xn@W1a+b1a)@W2a + b2 + x2
    gemm_bt<EPI_GELU, 768><<<dim3(12, 256), blk, 0, stream>>>(xn, w1T, b1, nullptr, ff1, 1536);
    gemm_bt<EPI_OUT1, 1536><<<dim3(6, 256), blk, 0, stream>>>(ff1, w2aT, b2, x2b, outp, 768);
    //    half 1: out += gelu(xn@W1b+b1b)@W2b
    gemm_bt<EPI_GELU, 768><<<dim3(12, 256), blk, 0, stream>>>(xn, w1T + (size_t)1536 * 768,
                                                             b1 + 1536, nullptr, ff1, 1536);
    gemm_bt<EPI_OUT2, 1536><<<dim3(6, 256), blk, 0, stream>>>(ff1, w2bT, nullptr, nullptr, outp, 768);
}

// Round 3
// 1096.436 us; speedup vs baseline: 1.4103x; 1.4103x over previous
//
#include <hip/hip_runtime.h>
#include <math.h>

// LinearBlock: x -> LN1 -> QKV -> linear attention -> Wo+bias+res -> LN2 -> FFN(gelu) -> +res
// B=4, T=8192, D=768, H=12, HD=64, DFF=3072. fp32 in/out; bf16 MFMA internally.
//
// Round-3 changes:
//  * ctx_kernel eliminated: att = diag(1/Z) * Q * (KV @ Wo). Per-(b,h) W2 = KV@Wo is
//    precomputed (tiny), Q is scaled in-place by 1/Z, and ctx+Wo become ONE GEMM with
//    per-batch weights.
//  * GEMM staging via global_load_lds width=16 into linear LDS (m97 structure),
//    XCD-aware bijective block swizzle.
//  * ksum fused into kv_partial.

#define DEV __device__ __forceinline__

typedef __attribute__((ext_vector_type(8))) short s16x8;   // 8 x bf16 (4 VGPRs)
typedef __attribute__((ext_vector_type(4))) float f32x4;   // MFMA accumulator

static constexpr int    Bb   = 4;
static constexpr int    Tt   = 8192;
static constexpr int    Dd   = 768;
static constexpr int    Hh   = 12;
static constexpr size_t Mrows = (size_t)Bb * Tt;           // 32768

DEV float bf2f(unsigned short u) {
    union { unsigned int i; float f; } c; c.i = ((unsigned int)u) << 16; return c.f;
}
DEV unsigned short f2bf(float f) {
    union { float f; unsigned int i; } c; c.f = f;
    unsigned int r = c.i + 0x7fffu + ((c.i >> 16) & 1u);   // RNE
    return (unsigned short)(r >> 16);
}

// async global(16B/lane) -> LDS (wave-uniform base + lane*16)
DEV void gload16(const unsigned short* g, unsigned short* l) {
    __builtin_amdgcn_global_load_lds(
        (const __attribute__((address_space(1))) void*)g,
        (__attribute__((address_space(3))) void*)l, 16, 0, 0);
}

// ---------------------------------------------------------------------------
// Transpose + convert: fp32 in[R][C] -> bf16 out[C][R]
// ---------------------------------------------------------------------------
__global__ __launch_bounds__(256)
void transpose_f2b(const float* __restrict__ in, unsigned short* __restrict__ out,
                   int R, int C) {
    __shared__ float tile[32][33];
    const int c0 = blockIdx.x * 32, r0 = blockIdx.y * 32;
    const int tx = threadIdx.x, ty = threadIdx.y;          // (32, 8)
    #pragma unroll
    for (int i = 0; i < 32; i += 8)
        tile[ty + i][tx] = in[(size_t)(r0 + ty + i) * C + c0 + tx];
    __syncthreads();
    #pragma unroll
    for (int i = 0; i < 32; i += 8)
        out[(size_t)(c0 + ty + i) * R + r0 + tx] = f2bf(tile[tx][ty + i]);
}

// ---------------------------------------------------------------------------
// LayerNorm over D=768 -> bf16. BF16IN: input dtype.
// ---------------------------------------------------------------------------
template <int BF16IN>
__global__ __launch_bounds__(256)
void ln_kernel(const void* __restrict__ xin, const float* __restrict__ g,
               const float* __restrict__ bvec, unsigned short* __restrict__ out) {
    __shared__ float red[4];
    const int tid = threadIdx.x;
    const size_t base = (size_t)blockIdx.x * Dd;
    float v[3];
    #pragma unroll
    for (int i = 0; i < 3; ++i) {
        const size_t idx = base + tid + i * 256;
        if (BF16IN) v[i] = bf2f(((const unsigned short*)xin)[idx]);
        else        v[i] = ((const float*)xin)[idx];
    }
    float s = v[0] + v[1] + v[2];
    #pragma unroll
    for (int o = 32; o >= 1; o >>= 1) s += __shfl_xor(s, o);
    if ((tid & 63) == 0) red[tid >> 6] = s;
    __syncthreads();
    s = red[0] + red[1] + red[2] + red[3];
    const float mu = s * (1.0f / Dd);
    __syncthreads();
    float q = 0.f;
    #pragma unroll
    for (int i = 0; i < 3; ++i) { const float d = v[i] - mu; q += d * d; }
    #pragma unroll
    for (int o = 32; o >= 1; o >>= 1) q += __shfl_xor(q, o);
    if ((tid & 63) == 0) red[tid >> 6] = q;
    __syncthreads();
    q = red[0] + red[1] + red[2] + red[3];
    const float rstd = rsqrtf(q * (1.0f / Dd) + 1e-5f);
    #pragma unroll
    for (int i = 0; i < 3; ++i) {
        const int c = tid + i * 256;
        out[base + c] = f2bf((v[i] - mu) * rstd * g[c] + bvec[c]);
    }
}

// ---------------------------------------------------------------------------
// GEMM: C[M,N] = A[M,K] @ BT[N,K]^T. bf16 in, fp32 acc, fused epilogue.
// 128x128 tile, 4 waves (2x2), linear LDS [128][32], global_load_lds staging,
// XCD-swizzled linear grid (requires nwg % 8 == 0). PB: per-batch BT (8192 rows/batch).
// ---------------------------------------------------------------------------
#define EPI_QKV  0   // out bf16 Q/K/V triple (each M*768), elu+1 on Q,K
#define EPI_X2   1   // out bf16 = acc + bias[col] + f32res[row,col]   (x2 = att + x)
#define EPI_GELU 2   // out bf16 = gelu(acc + bias[col])
#define EPI_OUT1 3   // out f32  = acc + bias[col] + bf16res[row,col]
#define EPI_OUT2 4   // out f32 += acc

template <int EPI, int K, int PB>
__global__ __launch_bounds__(256)
void gemm_bt(const unsigned short* __restrict__ A,
             const unsigned short* __restrict__ BT,
             const float* __restrict__ bias,
             const void* __restrict__ res,
             void* __restrict__ out, int N) {
    const int NT = N >> 7;
    const int nwg = gridDim.x;
    int wg = blockIdx.x;
    wg = (wg & 7) * (nwg >> 3) + (wg >> 3);            // XCD-contiguous tiles
    const int nt = wg % NT, mt = wg / NT;
    const int m0 = mt * 128, n0 = nt * 128;
    const int tid = threadIdx.x;
    const int lane = tid & 63, w = tid >> 6;
    const int wm = w >> 1, wn = w & 1;
    const int l15 = lane & 15, lk = lane >> 4;

    __shared__ __align__(16) unsigned short sA[128 * 32];   // linear, no padding
    __shared__ __align__(16) unsigned short sB[128 * 32];

    const unsigned short* BTb = PB ? (BT + (size_t)(m0 >> 13) * 768 * 768) : BT;

    // staging coords: wave w covers rows [w*32, w*32+32); instr j adds 16 rows.
    const int srow = w * 32 + (lane >> 2);
    const int scol = (lane & 3) * 8;
    const unsigned short* gA = A   + (size_t)(m0 + srow) * K + scol;
    const unsigned short* gB = BTb + (size_t)(n0 + srow) * K + scol;
    unsigned short* lA = &sA[w * 32 * 32];
    unsigned short* lB = &sB[w * 32 * 32];

    f32x4 acc[4][4] = {};

    for (int kt = 0; kt < K; kt += 32) {
        gload16(gA + kt,              lA);
        gload16(gA + kt + 16 * K,     lA + 16 * 32);
        gload16(gB + kt,              lB);
        gload16(gB + kt + 16 * K,     lB + 16 * 32);
        __syncthreads();                                // vmcnt drain + barrier
        s16x8 af[4], bf[4];
        #pragma unroll
        for (int i = 0; i < 4; ++i) {
            af[i] = *(const s16x8*)(&sA[(wm * 64 + i * 16 + l15) * 32 + lk * 8]);
            bf[i] = *(const s16x8*)(&sB[(wn * 64 + i * 16 + l15) * 32 + lk * 8]);
        }
        #pragma unroll
        for (int i = 0; i < 4; ++i)
            #pragma unroll
            for (int j = 0; j < 4; ++j)
                acc[i][j] = __builtin_amdgcn_mfma_f32_16x16x32_bf16(af[i], bf[j], acc[i][j], 0, 0, 0);
        __syncthreads();
    }

    // D frag mapping: col = lane&15, row = (lane>>4)*4 + r
    #pragma unroll
    for (int i = 0; i < 4; ++i) {
        #pragma unroll
        for (int j = 0; j < 4; ++j) {
            const int col = n0 + wn * 64 + j * 16 + l15;
            #pragma unroll
            for (int r = 0; r < 4; ++r) {
                const int row = m0 + wm * 64 + i * 16 + lk * 4 + r;
                float v = acc[i][j][r];
                if (EPI == EPI_QKV) {
                    const int which = col / 768;
                    const int cc = col - which * 768;
                    if (which < 2) v = (v > 0.f) ? (v + 1.f) : __expf(v);   // elu(v)+1
                    ((unsigned short*)out)[(size_t)which * (Mrows * Dd) + (size_t)row * Dd + cc] = f2bf(v);
                } else if (EPI == EPI_X2) {
                    v += bias[col] + ((const float*)res)[(size_t)row * N + col];
                    ((unsigned short*)out)[(size_t)row * N + col] = f2bf(v);
                } else if (EPI == EPI_GELU) {
                    v += bias[col];
                    v = 0.5f * v * (1.0f + erff(v * 0.70710678118654752f));
                    ((unsigned short*)out)[(size_t)row * N + col] = f2bf(v);
                } else if (EPI == EPI_OUT1) {
                    v += bias[col] + bf2f(((const unsigned short*)res)[(size_t)row * N + col]);
                    ((float*)out)[(size_t)row * N + col] = v;
                } else {  // EPI_OUT2
                    ((float*)out)[(size_t)row * N + col] += v;
                }
            }
        }
    }
}

// ---------------------------------------------------------------------------
// Partial KV + partial Ksum per 1024-t chunk.
// part[bh][ck][d][e] = sum_t K[t,d]V[t,e];  pksum[bh][ck][d] = sum_t K[t,d]
// ---------------------------------------------------------------------------
__global__ __launch_bounds__(256)
void kv_partial(const unsigned short* __restrict__ Km, const unsigned short* __restrict__ Vm,
                float* __restrict__ part, float* __restrict__ pksum) {
    const int ck = blockIdx.x, bh = blockIdx.y;
    const int b = bh / Hh, h = bh - b * Hh;
    const int tid = threadIdx.x;
    const int e = tid & 63, dg = tid >> 6;               // wave-uniform dg
    __shared__ float sK[32][64], sV[32][64];
    float acc[16] = {};
    float ksacc = 0.f;
    const size_t rowbase = ((size_t)b * Tt + (size_t)ck * 1024) * Dd + h * 64;
    const int rw = tid >> 3, cv = (tid & 7) * 8;
    for (int ts = 0; ts < 1024; ts += 32) {
        const s16x8 k8 = *(const s16x8*)(Km + rowbase + (size_t)(ts + rw) * Dd + cv);
        const s16x8 v8 = *(const s16x8*)(Vm + rowbase + (size_t)(ts + rw) * Dd + cv);
        float kf[8], vf[8];
        #pragma unroll
        for (int j = 0; j < 8; ++j) {
            kf[j] = bf2f((unsigned short)k8[j]);
            vf[j] = bf2f((unsigned short)v8[j]);
        }
        __syncthreads();
        *(float4*)(&sK[rw][cv])     = *(const float4*)&kf[0];
        *(float4*)(&sK[rw][cv + 4]) = *(const float4*)&kf[4];
        *(float4*)(&sV[rw][cv])     = *(const float4*)&vf[0];
        *(float4*)(&sV[rw][cv + 4]) = *(const float4*)&vf[4];
        __syncthreads();
        #pragma unroll 4
        for (int tt = 0; tt < 32; ++tt) {
            const float vv = sV[tt][e];
            const float4* kp = (const float4*)(&sK[tt][dg * 16]);
            const float4 k0 = kp[0], k1 = kp[1], k2 = kp[2], k3 = kp[3];
            acc[0]  += k0.x * vv; acc[1]  += k0.y * vv; acc[2]  += k0.z * vv; acc[3]  += k0.w * vv;
            acc[4]  += k1.x * vv; acc[5]  += k1.y * vv; acc[6]  += k1.z * vv; acc[7]  += k1.w * vv;
            acc[8]  += k2.x * vv; acc[9]  += k2.y * vv; acc[10] += k2.z * vv; acc[11] += k2.w * vv;
            acc[12] += k3.x * vv; acc[13] += k3.y * vv; acc[14] += k3.z * vv; acc[15] += k3.w * vv;
        }
        if (dg == 0) {
            #pragma unroll 4
            for (int tt = 0; tt < 32; ++tt) ksacc += sK[tt][e];
        }
    }
    float* op = part + ((size_t)bh * 8 + ck) * 4096 + (size_t)dg * 16 * 64 + e;
    #pragma unroll
    for (int i = 0; i < 16; ++i) op[(size_t)i * 64] = acc[i];
    if (dg == 0) pksum[((size_t)bh * 8 + ck) * 64 + e] = ksacc;
}

__global__ __launch_bounds__(256)
void kv_reduce(const float* __restrict__ part, const float* __restrict__ pksum,
               float* __restrict__ kv, float* __restrict__ ksum) {
    const int bh = blockIdx.x;
    const int tid = threadIdx.x;
    #pragma unroll
    for (int j = 0; j < 16; ++j) {
        const int i = j * 256 + tid;
        float s = 0.f;
        #pragma unroll
        for (int c = 0; c < 8; ++c) s += part[((size_t)bh * 8 + c) * 4096 + i];
        kv[(size_t)bh * 4096 + i] = s;
    }
    if (tid < 64) {
        float s = 0.f;
        #pragma unroll
        for (int c = 0; c < 8; ++c) s += pksum[((size_t)bh * 8 + c) * 64 + tid];
        ksum[(size_t)bh * 64 + tid] = s;
    }
}

// ---------------------------------------------------------------------------
// Qs = Q / (Q . Ksum + eps), in place. One block per row; each 64-lane wave
// covers exactly one head's 64 dims -> wave reduce gives Z.
// ---------------------------------------------------------------------------
__global__ __launch_bounds__(256)
void qscale_kernel(unsigned short* __restrict__ Q, const float* __restrict__ ksum) {
    const int row = blockIdx.x;
    const int b = row >> 13;
    const int tid = threadIdx.x, lane = tid & 63;
    const size_t base = (size_t)row * Dd;
    #pragma unroll
    for (int i = 0; i < 3; ++i) {
        const int c = i * 256 + tid;
        const int h = c >> 6;
        const float q = bf2f(Q[base + c]);
        float zp = q * ksum[((size_t)b * Hh + h) * 64 + lane];
        #pragma unroll
        for (int o = 32; o >= 1; o >>= 1) zp += __shfl_xor(zp, o);
        const float zi = 1.0f / (zp + 1e-6f);
        Q[base + c] = f2bf(q * zi);
    }
}

// ---------------------------------------------------------------------------
// W2T[b][n][h*64+d] = sum_e KV_bh[d][e] * Wo[h*64+e][n]  (= woT[n][h*64+e])
// grid (48, 4): block handles one (b,h) and a 192-wide n-range.
// ---------------------------------------------------------------------------
__global__ __launch_bounds__(256)
void w2_build(const float* __restrict__ kvf, const unsigned short* __restrict__ woT,
              unsigned short* __restrict__ W2T) {
    const int bh = blockIdx.x, ny = blockIdx.y;
    const int b = bh / Hh, h = bh - b * Hh;
    __shared__ float sKV[64][65];
    const int tid = threadIdx.x;
    for (int i = tid; i < 4096; i += 256) sKV[i >> 6][i & 63] = kvf[(size_t)bh * 4096 + i];
    __syncthreads();
    const int d = tid & 63, ng = tid >> 6;
    #pragma unroll 4
    for (int i = 0; i < 48; ++i) {
        const int n = ny * 192 + i * 4 + ng;           // wave-uniform
        const unsigned short* wr = woT + (size_t)n * Dd + h * 64;
        float a = 0.f;
        #pragma unroll
        for (int e = 0; e < 64; ++e) a += bf2f(wr[e]) * sKV[d][e];
        W2T[((size_t)b * Dd + n) * Dd + h * 64 + d] = f2bf(a);
    }
}

// ---------------------------------------------------------------------------
extern "C" void kernel_launch(void* const* d_in, const int* in_sizes, int n_in,
                              void* d_out, int out_size, void* d_ws, size_t ws_size,
                              hipStream_t stream) {
    (void)in_sizes; (void)n_in; (void)out_size; (void)ws_size;
    const float* x    = (const float*)d_in[0];
    const float* Wq   = (const float*)d_in[1];
    const float* Wk   = (const float*)d_in[2];
    const float* Wv   = (const float*)d_in[3];
    const float* Wo   = (const float*)d_in[4];
    const float* bo   = (const float*)d_in[5];
    const float* ln1g = (const float*)d_in[6];
    const float* ln1b = (const float*)d_in[7];
    const float* ln2g = (const float*)d_in[8];
    const float* ln2b = (const float*)d_in[9];
    const float* W1   = (const float*)d_in[10];
    const float* b1   = (const float*)d_in[11];
    const float* W2   = (const float*)d_in[12];
    const float* b2   = (const float*)d_in[13];
    float* outp = (float*)d_out;

    // workspace (~223 MiB, same footprint as round 2)
    char* ws = (char*)d_ws;
    const size_t SZ = Mrows * Dd * 2;                           // bf16 [M][768] slot
    unsigned short* xn = (unsigned short*)(ws + 0);             // s0: LN out
    unsigned short* Qb = (unsigned short*)(ws + SZ);            // s1: Q/Qs, later ff1-lo
    unsigned short* Kb = (unsigned short*)(ws + 2 * SZ);        // s2: K,   later ff1-hi
    unsigned short* Vb = (unsigned short*)(ws + 3 * SZ);        // s3: V,   later x2 bf16
    char* p = ws + 4 * SZ;
    float* part  = (float*)p;  p += (size_t)48 * 8 * 4096 * 4;  // 6.3 MB (later: W2T)
    float* kvf   = (float*)p;  p += (size_t)48 * 4096 * 4;
    float* ksumf = (float*)p;  p += (size_t)48 * 64 * 4;
    unsigned short* wqkvT = (unsigned short*)p; p += (size_t)2304 * 768 * 2;
    unsigned short* woT   = (unsigned short*)p; p += (size_t)768 * 768 * 2;
    unsigned short* w1T   = (unsigned short*)p; p += (size_t)3072 * 768 * 2;
    unsigned short* w2aT  = (unsigned short*)p; p += (size_t)768 * 1536 * 2;
    unsigned short* w2bT  = (unsigned short*)p; p += (size_t)768 * 1536 * 2;
    float* pksum = (float*)p;  p += (size_t)48 * 8 * 64 * 4;
    unsigned short* W2T = (unsigned short*)part;   // part dead after kv_reduce (4.5 MB of 6.3)
    unsigned short* ff1 = Qb;                      // M x 1536 bf16 = slots s1+s2
    unsigned short* x2b = Vb;

    const dim3 blk(256);
    const dim3 tb(32, 8);

    // 1) weight transposes + bf16 convert
    transpose_f2b<<<dim3(24, 24), tb, 0, stream>>>(Wq, wqkvT, 768, 768);
    transpose_f2b<<<dim3(24, 24), tb, 0, stream>>>(Wk, wqkvT + 589824, 768, 768);
    transpose_f2b<<<dim3(24, 24), tb, 0, stream>>>(Wv, wqkvT + 2 * 589824, 768, 768);
    transpose_f2b<<<dim3(24, 24), tb, 0, stream>>>(Wo, woT, 768, 768);
    transpose_f2b<<<dim3(96, 24), tb, 0, stream>>>(W1, w1T, 768, 3072);
    transpose_f2b<<<dim3(24, 48), tb, 0, stream>>>(W2, w2aT, 1536, 768);
    transpose_f2b<<<dim3(24, 48), tb, 0, stream>>>(W2 + (size_t)1536 * 768, w2bT, 1536, 768);

    // 2) LN1
    ln_kernel<0><<<32768, blk, 0, stream>>>(x, ln1g, ln1b, xn);

    // 3) fused QKV projection (N=2304), elu+1 on Q,K
    gemm_bt<EPI_QKV, 768, 0><<<4608, blk, 0, stream>>>(xn, wqkvT, nullptr, nullptr, Qb, 2304);

    // 4) linear-attention stats: KV and Ksum
    kv_partial<<<dim3(8, 48), blk, 0, stream>>>(Kb, Vb, part, pksum);
    kv_reduce<<<48, blk, 0, stream>>>(part, pksum, kvf, ksumf);

    // 5) Qs = Q/Z (in place); W2 = KV @ Wo (per b,h)
    qscale_kernel<<<32768, blk, 0, stream>>>(Qb, ksumf);
    w2_build<<<dim3(48, 4), blk, 0, stream>>>(kvf, woT, W2T);

    // 6) att + bias + residual(x) -> x2 bf16 : one GEMM, per-batch weights
    gemm_bt<EPI_X2, 768, 1><<<1536, blk, 0, stream>>>(Qb, W2T, bo, x, x2b, 768);

    // 7) LN2
    ln_kernel<1><<<32768, blk, 0, stream>>>(x2b, ln2g, ln2b, xn);

    // 8) FFN in two halves (ff1 = M x 1536 bf16 in s1+s2)
    gemm_bt<EPI_GELU, 768, 0><<<3072, blk, 0, stream>>>(xn, w1T, b1, nullptr, ff1, 1536);
    gemm_bt<EPI_OUT1, 1536, 0><<<1536, blk, 0, stream>>>(ff1, w2aT, b2, x2b, outp, 768);
    gemm_bt<EPI_GELU, 768, 0><<<3072, blk, 0, stream>>>(xn, w1T + (size_t)1536 * 768,
                                                        b1 + 1536, nullptr, ff1, 1536);
    gemm_bt<EPI_OUT2, 1536, 0><<<1536, blk, 0, stream>>>(ff1, w2bT, nullptr, nullptr, outp, 768);
}